// Round 8
// baseline (623.345 us; speedup 1.0000x reference)
//
#include <hip/hip_runtime.h>
#include <hip/hip_bf16.h>

#define T_SEQ 1024
#define CHUNK 64
#define NCHUNK (T_SEQ / CHUNK)   // 16

__device__ __forceinline__ float fast_sigmoid(float x) {
    return 1.0f / (1.0f + __expf(-x));
}
__device__ __forceinline__ float fast_tanh(float x) {
    float e = __expf(2.0f * x);
    return 1.0f - 2.0f / (e + 1.0f);
}

// ---- packed weight block layout (floats), produced by k_repack ----
#define L_XW1 0       // 20 rows of 68: {w_t,pad,pad,pad, w_x0..63}
#define L_UW1 1360
#define L_XW2 2720    // 20 rows of 20
#define L_UW2 3120
#define L_XW3 3520    // 64 rows of 20
#define L_UW3 4800
#define L_CWT 6080    // cwT[128][64]: cwT[j][s] = cw[s*128+j]
#define L_XB1 14272
#define L_XB2 14292
#define L_UB1 14312
#define L_UB2 14332
#define L_XB3 14352
#define L_UB3 14416
#define L_CB  14480
#define L_TOT 14544   // 58176 bytes

__global__ __launch_bounds__(256) void k_repack(
    const float* __restrict__ xw1, const float* __restrict__ uw1,
    const float* __restrict__ xw2, const float* __restrict__ uw2,
    const float* __restrict__ xw3, const float* __restrict__ uw3,
    const float* __restrict__ cw,
    const float* __restrict__ xb1, const float* __restrict__ xb2,
    const float* __restrict__ ub1, const float* __restrict__ ub2,
    const float* __restrict__ xb3, const float* __restrict__ ub3,
    const float* __restrict__ cb, float* __restrict__ wp) {
    int i = blockIdx.x * 256 + threadIdx.x;
    if (i >= L_TOT) return;
    float v = 0.0f;
    if (i < 1360) {
        int o = i / 68, c = i - o * 68;
        if (c == 0) v = xw1[o * 65];
        else if (c >= 4) v = xw1[o * 65 + c - 3];
    } else if (i < 2720) {
        int j = i - 1360; int o = j / 68, c = j - o * 68;
        if (c == 0) v = uw1[o * 65];
        else if (c >= 4) v = uw1[o * 65 + c - 3];
    } else if (i < 3120) v = xw2[i - 2720];
    else if (i < 3520) v = uw2[i - 3120];
    else if (i < 4800) v = xw3[i - 3520];
    else if (i < 6080) v = uw3[i - 4800];
    else if (i < 14272) {
        int j = i - 6080; int row = j >> 6, s = j & 63;
        v = cw[s * 128 + row];
    }
    else if (i < 14292) v = xb1[i - 14272];
    else if (i < 14312) v = xb2[i - 14292];
    else if (i < 14332) v = ub1[i - 14312];
    else if (i < 14352) v = ub2[i - 14332];
    else if (i < 14416) v = xb3[i - 14352];
    else if (i < 14480) v = ub3[i - 14416];
    else v = cb[i - 14480];
    wp[i] = v;
}

// ---- shared MLP helpers (read LDS weight block) ----
template <int OW1, int OB1, int OW2, int OB2>
__device__ __forceinline__ void mlp20(const float* __restrict__ sm,
                                      float tval, const float4* z, float* h2) {
    float h1[20];
#pragma unroll 4
    for (int o = 0; o < 20; ++o) {
        const int ro = OW1 + o * 68;
        float a = sm[OB1 + o] + tval * sm[ro];
        const float4* wr = reinterpret_cast<const float4*>(&sm[ro + 4]);
#pragma unroll
        for (int v = 0; v < 16; ++v) {
            float4 w4 = wr[v];
            a += z[v].x * w4.x + z[v].y * w4.y + z[v].z * w4.z + z[v].w * w4.w;
        }
        h1[o] = fast_sigmoid(a);
    }
#pragma unroll 4
    for (int o = 0; o < 20; ++o) {
        float a = sm[OB2 + o];
        const float4* wr = reinterpret_cast<const float4*>(&sm[OW2 + o * 20]);
#pragma unroll
        for (int v = 0; v < 5; ++v) {
            float4 w4 = wr[v];
            a += h2[0] * 0.0f  // (no-op to keep shape; optimized away)
               + h1[4*v+0]*w4.x + h1[4*v+1]*w4.y + h1[4*v+2]*w4.z + h1[4*v+3]*w4.w;
        }
        h2[o] = fast_sigmoid(a);
    }
}

template <int OW3, int OB3, int OCWT>
__device__ __forceinline__ void final64(const float* __restrict__ sm,
                                        const float* h2, float* oacc) {
#pragma unroll 2
    for (int o = 0; o < 64; ++o) {
        float a = sm[OB3 + o];
        const float4* wr = reinterpret_cast<const float4*>(&sm[OW3 + o * 20]);
#pragma unroll
        for (int v = 0; v < 5; ++v) {
            float4 w4 = wr[v];
            a += h2[4*v+0]*w4.x + h2[4*v+1]*w4.y + h2[4*v+2]*w4.z + h2[4*v+3]*w4.w;
        }
        float s = fast_sigmoid(a);
        const float4* cr = reinterpret_cast<const float4*>(&sm[OCWT + o * 64]);
#pragma unroll
        for (int v = 0; v < 16; ++v) {
            float4 c4 = cr[v];
            oacc[4*v+0] += s * c4.x; oacc[4*v+1] += s * c4.y;
            oacc[4*v+2] += s * c4.z; oacc[4*v+3] += s * c4.w;
        }
    }
}

// ---- K_MAIN: block 0 = RNN chain (2 specialized waves); blocks 1..1024 = state branch
// chain LDS layout inside smem:
//   pre[2][4096]    @ 0      (pre_i chunks)
//   hs [2][4096]    @ 8192   (h after each local step)
//   u3 [3][512]     @ 16384  (u chunks, triple-buffered)
//   hcarry[4][64]   @ 17920  (chunk-final h, rotating)
// state blocks: wp weight block @ 0 (14544 floats)
#define SMEM_FLOATS 18176

__global__ __launch_bounds__(256) void k_main(
    const float* __restrict__ t_in, const float* __restrict__ x_in,
    const float* __restrict__ u,
    const float* __restrict__ i2h_w, const float* __restrict__ i2h_b,
    const float* __restrict__ h2o_w, const float* __restrict__ h2o_b,
    const float* __restrict__ wp,
    float* __restrict__ uo, float* __restrict__ out) {
    __shared__ float smem[SMEM_FLOATS];
    const int tid = threadIdx.x;
    const int bid = blockIdx.x;

    if (bid == 0) {
        float* pre = smem;
        float* hs = smem + 8192;
        float* u3 = smem + 16384;
        float* hcarry = smem + 17920;
        const int lane = tid & 63;
        const int wv = tid >> 6;

        if (wv == 0) {
            // ---- serial chain wave: readlane h-broadcast, ~2 LDS ops/step ----
            float wih[64];
#pragma unroll
            for (int j = 0; j < 64; ++j) wih[j] = i2h_w[lane * 72 + 8 + j];
            float h = 0.0f;
            __syncthreads();                     // B0: pre chunk 0 ready
            for (int c = 0; c < NCHUNK; ++c) {
                const float* pb = pre + (c & 1) * 4096;
                float* hw = hs + (c & 1) * 4096;
#pragma unroll 2
                for (int s = 0; s < CHUNK; ++s) {
                    float pcur = pb[s * 64 + lane];
                    int hb = __float_as_int(h);
                    float a0 = pcur, a1 = 0.0f, a2 = 0.0f, a3 = 0.0f;
#pragma unroll
                    for (int j = 0; j < 64; j += 4) {
                        a0 += wih[j+0] * __int_as_float(__builtin_amdgcn_readlane(hb, j+0));
                        a1 += wih[j+1] * __int_as_float(__builtin_amdgcn_readlane(hb, j+1));
                        a2 += wih[j+2] * __int_as_float(__builtin_amdgcn_readlane(hb, j+2));
                        a3 += wih[j+3] * __int_as_float(__builtin_amdgcn_readlane(hb, j+3));
                    }
                    h = fast_tanh((a0 + a1) + (a2 + a3));
                    hw[s * 64 + lane] = h;
                    if (s == CHUNK - 1) hcarry[(c & 3) * 64 + lane] = h;
                }
                __syncthreads();                 // chunk c published
            }
        } else if (wv == 1) {
            // ---- stager wave: u->pre producer, hs->uo consumer ----
            float who[64];
#pragma unroll
            for (int m = 0; m < 64; ++m) who[m] = h2o_w[lane * 72 + 8 + m];
            float wiu[8], wou[8];
#pragma unroll
            for (int c8 = 0; c8 < 8; ++c8) {
                wiu[c8] = i2h_w[lane * 72 + c8];
                wou[c8] = h2o_w[lane * 72 + c8];
            }
            const float bi = i2h_b[lane], bo = h2o_b[lane];
            // prologue: stage u chunk 0, compute pre chunk 0, zero hcarry[3]
            {
                const float4* ug = reinterpret_cast<const float4*>(u);
                float4* ud = reinterpret_cast<float4*>(u3);
#pragma unroll
                for (int it = 0; it < 2; ++it) ud[it * 64 + lane] = ug[it * 64 + lane];
                hcarry[3 * 64 + lane] = 0.0f;
            }
            // compute pre chunk 0 (needs u3[0] visible to this wave only - same wave, fine)
            {
                const float* ub = u3;
#pragma unroll 4
                for (int s = 0; s < CHUNK; ++s) {
                    const float4 ua = *reinterpret_cast<const float4*>(&ub[s * 8]);
                    const float4 ubv = *reinterpret_cast<const float4*>(&ub[s * 8 + 4]);
                    float a = bi + ua.x*wiu[0] + ua.y*wiu[1] + ua.z*wiu[2] + ua.w*wiu[3]
                                 + ubv.x*wiu[4] + ubv.y*wiu[5] + ubv.z*wiu[6] + ubv.w*wiu[7];
                    pre[s * 64 + lane] = a;
                }
            }
            __syncthreads();                     // B0
            for (int c = 0; c < NCHUNK; ++c) {
                if (c + 1 < NCHUNK) {
                    // stage u chunk c+1 into u3 slot (c+1)%3
                    const float4* ug = reinterpret_cast<const float4*>(u + (c + 1) * 512);
                    float4* ud = reinterpret_cast<float4*>(u3 + ((c + 1) % 3) * 512);
#pragma unroll
                    for (int it = 0; it < 2; ++it) ud[it * 64 + lane] = ug[it * 64 + lane];
                    // compute pre chunk c+1 into pre[(c+1)&1]
                    const float* ub = u3 + ((c + 1) % 3) * 512;
                    float* pd = pre + ((c + 1) & 1) * 4096;
#pragma unroll 4
                    for (int s = 0; s < CHUNK; ++s) {
                        const float4 ua = *reinterpret_cast<const float4*>(&ub[s * 8]);
                        const float4 ubv = *reinterpret_cast<const float4*>(&ub[s * 8 + 4]);
                        float a = bi + ua.x*wiu[0] + ua.y*wiu[1] + ua.z*wiu[2] + ua.w*wiu[3]
                                     + ubv.x*wiu[4] + ubv.y*wiu[5] + ubv.z*wiu[6] + ubv.w*wiu[7];
                        pd[s * 64 + lane] = a;
                    }
                }
                if (c >= 1) {
                    // uo rows for chunk cm = c-1 (hs[(c-1)&1] stable now)
                    const int cm = c - 1;
                    const float* hsb = hs + (cm & 1) * 4096;
                    const float* ub = u3 + (cm % 3) * 512;
                    float* uop = uo + cm * CHUNK * 64;
#pragma unroll 2
                    for (int s = 0; s < CHUNK; ++s) {
                        const float4* h4 = (s == 0)
                            ? reinterpret_cast<const float4*>(hcarry + ((cm - 1) & 3) * 64)
                            : reinterpret_cast<const float4*>(&hsb[(s - 1) * 64]);
                        const float4 ua = *reinterpret_cast<const float4*>(&ub[s * 8]);
                        const float4 ubv = *reinterpret_cast<const float4*>(&ub[s * 8 + 4]);
                        float a = bo + ua.x*wou[0] + ua.y*wou[1] + ua.z*wou[2] + ua.w*wou[3]
                                     + ubv.x*wou[4] + ubv.y*wou[5] + ubv.z*wou[6] + ubv.w*wou[7];
#pragma unroll
                        for (int v = 0; v < 16; ++v) {
                            float4 hv = h4[v];
                            a += who[4*v+0]*hv.x + who[4*v+1]*hv.y
                               + who[4*v+2]*hv.z + who[4*v+3]*hv.w;
                        }
                        uop[s * 64 + lane] = fast_tanh(a);
                    }
                }
                __syncthreads();
            }
            {   // epilogue: uo rows for final chunk
                const int cm = NCHUNK - 1;
                const float* hsb = hs + (cm & 1) * 4096;
                const float* ub = u3 + (cm % 3) * 512;
                float* uop = uo + cm * CHUNK * 64;
#pragma unroll 2
                for (int s = 0; s < CHUNK; ++s) {
                    const float4* h4 = (s == 0)
                        ? reinterpret_cast<const float4*>(hcarry + ((cm - 1) & 3) * 64)
                        : reinterpret_cast<const float4*>(&hsb[(s - 1) * 64]);
                    const float4 ua = *reinterpret_cast<const float4*>(&ub[s * 8]);
                    const float4 ubv = *reinterpret_cast<const float4*>(&ub[s * 8 + 4]);
                    float a = bo + ua.x*wou[0] + ua.y*wou[1] + ua.z*wou[2] + ua.w*wou[3]
                                 + ubv.x*wou[4] + ubv.y*wou[5] + ubv.z*wou[6] + ubv.w*wou[7];
#pragma unroll
                    for (int v = 0; v < 16; ++v) {
                        float4 hv = h4[v];
                        a += who[4*v+0]*hv.x + who[4*v+1]*hv.y
                           + who[4*v+2]*hv.z + who[4*v+3]*hv.w;
                    }
                    uop[s * 64 + lane] = fast_tanh(a);
                }
            }
        } else {
            // barrier-matching idle waves (17 barriers total)
            for (int c = 0; c <= NCHUNK; ++c) __syncthreads();
        }
        return;
    }

    // ---- state-branch blocks ----
    {
        float4* s4 = reinterpret_cast<float4*>(smem);
        const float4* w4 = reinterpret_cast<const float4*>(wp);
        for (int idx = tid; idx < L_TOT / 4; idx += 256) s4[idx] = w4[idx];
    }
    __syncthreads();

    const int r = (bid - 1) * 256 + tid;
    float tval = t_in[r];
    float4 z[16];
    const float4* xp = reinterpret_cast<const float4*>(x_in + (size_t)r * 64);
#pragma unroll
    for (int v = 0; v < 16; ++v) z[v] = xp[v];

    float h2[20];
    mlp20<L_XW1, L_XB1, L_XW2, L_XB2>(smem, tval, z, h2);

    float oacc[64];
    {
        const float4* cbp = reinterpret_cast<const float4*>(&smem[L_CB]);
#pragma unroll
        for (int v = 0; v < 16; ++v) {
            float4 c4 = cbp[v];
            oacc[4*v+0] = c4.x; oacc[4*v+1] = c4.y;
            oacc[4*v+2] = c4.z; oacc[4*v+3] = c4.w;
        }
    }
    final64<L_XW3, L_XB3, L_CWT>(smem, h2, oacc);

    float4* op = reinterpret_cast<float4*>(out + (size_t)r * 64);
#pragma unroll
    for (int v = 0; v < 16; ++v) {
        float4 f;
        f.x = oacc[4*v+0]; f.y = oacc[4*v+1];
        f.z = oacc[4*v+2]; f.w = oacc[4*v+3];
        op[v] = f;
    }
}

// ---- K_CTRL: control branch, accumulates into out ----
__global__ __launch_bounds__(256) void k_ctrl(
    const float* __restrict__ t_in, const float* __restrict__ uo,
    const float* __restrict__ wp, float* __restrict__ out) {
    __shared__ float sm[L_TOT];
    const int tid = threadIdx.x;
    {
        float4* s4 = reinterpret_cast<float4*>(sm);
        const float4* w4 = reinterpret_cast<const float4*>(wp);
        for (int idx = tid; idx < L_TOT / 4; idx += 256) s4[idx] = w4[idx];
    }
    __syncthreads();

    const int r = blockIdx.x * 256 + tid;
    float tval = t_in[r];
    int ti = min((int)(tval * 1024.0f), 1023);
    float4 z[16];
    const float4* ep = reinterpret_cast<const float4*>(uo + ti * 64);
#pragma unroll
    for (int v = 0; v < 16; ++v) z[v] = ep[v];

    float h2[20];
    mlp20<L_UW1, L_UB1, L_UW2, L_UB2>(sm, tval, z, h2);

    float oacc[64];
    float4* op = reinterpret_cast<float4*>(out + (size_t)r * 64);
#pragma unroll
    for (int v = 0; v < 16; ++v) {
        float4 f = op[v];
        oacc[4*v+0] = f.x; oacc[4*v+1] = f.y;
        oacc[4*v+2] = f.z; oacc[4*v+3] = f.w;
    }
    final64<L_UW3, L_UB3, L_CWT + 64 * 64>(sm, h2, oacc);
#pragma unroll
    for (int v = 0; v < 16; ++v) {
        float4 f;
        f.x = oacc[4*v+0]; f.y = oacc[4*v+1];
        f.z = oacc[4*v+2]; f.w = oacc[4*v+3];
        op[v] = f;
    }
}

extern "C" void kernel_launch(void* const* d_in, const int* in_sizes, int n_in,
                              void* d_out, int out_size, void* d_ws, size_t ws_size,
                              hipStream_t stream) {
    const float* t     = (const float*)d_in[0];
    const float* x     = (const float*)d_in[1];
    const float* u     = (const float*)d_in[2];
    const float* i2h_w = (const float*)d_in[3];
    const float* i2h_b = (const float*)d_in[4];
    const float* h2o_w = (const float*)d_in[5];
    const float* h2o_b = (const float*)d_in[6];
    const float* xw1 = (const float*)d_in[7];  const float* xb1 = (const float*)d_in[8];
    const float* xw2 = (const float*)d_in[9];  const float* xb2 = (const float*)d_in[10];
    const float* xw3 = (const float*)d_in[11]; const float* xb3 = (const float*)d_in[12];
    const float* uw1 = (const float*)d_in[13]; const float* ub1 = (const float*)d_in[14];
    const float* uw2 = (const float*)d_in[15]; const float* ub2 = (const float*)d_in[16];
    const float* uw3 = (const float*)d_in[17]; const float* ub3 = (const float*)d_in[18];
    const float* cw  = (const float*)d_in[19]; const float* cb  = (const float*)d_in[20];
    float* out = (float*)d_out;

    float* ws = (float*)d_ws;
    float* uo = ws;                    // [0, 65536) floats
    float* wp = ws + 65536;            // [65536, 80080)

    int Bv = in_sizes[0];              // 262144

    hipLaunchKernelGGL(k_repack, dim3((L_TOT + 255) / 256), dim3(256), 0, stream,
                       xw1, uw1, xw2, uw2, xw3, uw3, cw,
                       xb1, xb2, ub1, ub2, xb3, ub3, cb, wp);
    hipLaunchKernelGGL(k_main, dim3(1 + Bv / 256), dim3(256), 0, stream,
                       t, x, u, i2h_w, i2h_b, h2o_w, h2o_b, wp, uo, out);
    hipLaunchKernelGGL(k_ctrl, dim3(Bv / 256), dim3(256), 0, stream,
                       t, uo, wp, out);
}

// Round 9
// 438.540 us; speedup vs baseline: 1.4214x; 1.4214x over previous
//
#include <hip/hip_runtime.h>
#include <hip/hip_bf16.h>

#define T_SEQ 1024
#define CHUNK 64
#define NCHUNK (T_SEQ / CHUNK)   // 16

__device__ __forceinline__ float fast_sigmoid(float x) {
    return 1.0f / (1.0f + __expf(-x));
}
__device__ __forceinline__ float fast_tanh(float x) {
    float e = __expf(2.0f * x);
    return 1.0f - 2.0f / (e + 1.0f);
}

// K1: precompute u-dependent parts of both RNN linears (+bias)
__global__ __launch_bounds__(256) void k_rnn_pre(
    const float* __restrict__ u,
    const float* __restrict__ i2h_w, const float* __restrict__ i2h_b,
    const float* __restrict__ h2o_w, const float* __restrict__ h2o_b,
    float* __restrict__ pre_i, float* __restrict__ pre_o) {
    int idx = blockIdx.x * 256 + threadIdx.x;   // 0..65535
    int k = idx >> 6, i = idx & 63;
    float a = i2h_b[i], b = h2o_b[i];
#pragma unroll
    for (int c = 0; c < 8; ++c) {
        float uv = u[k * 8 + c];
        a += uv * i2h_w[i * 72 + c];
        b += uv * h2o_w[i * 72 + c];
    }
    pre_i[idx] = a;
    pre_o[idx] = b;
}

// K3: all RNN outputs in parallel (hseq[k] = h BEFORE step k)
__global__ __launch_bounds__(64) void k_rnn_out(
    const float* __restrict__ h2o_w,
    const float* __restrict__ pre_o,
    const float* __restrict__ hseq,
    float* __restrict__ uout) {
    int k = blockIdx.x, i = threadIdx.x;
    __shared__ float hk[64];
    hk[i] = hseq[k * 64 + i];
    __syncthreads();
    float acc = pre_o[k * 64 + i];
#pragma unroll
    for (int m = 0; m < 64; ++m) acc += h2o_w[i * 72 + 8 + m] * hk[m];
    uout[k * 64 + i] = fast_tanh(acc);
}

// ---- packed weight block layout (floats), produced by k_repack ----
#define L_XW1 0       // 20 rows of 68: {w_t,pad,pad,pad, w_x0..63}
#define L_UW1 1360
#define L_XW2 2720    // 20 rows of 20
#define L_UW2 3120
#define L_XW3 3520    // 64 rows of 20
#define L_UW3 4800
#define L_CWT 6080    // cwT[128][64]: cwT[j][s] = cw[s*128+j]
#define L_XB1 14272
#define L_XB2 14292
#define L_UB1 14312
#define L_UB2 14332
#define L_XB3 14352
#define L_UB3 14416
#define L_CB  14480
#define L_TOT 14544   // 58176 bytes

__global__ __launch_bounds__(256) void k_repack(
    const float* __restrict__ xw1, const float* __restrict__ uw1,
    const float* __restrict__ xw2, const float* __restrict__ uw2,
    const float* __restrict__ xw3, const float* __restrict__ uw3,
    const float* __restrict__ cw,
    const float* __restrict__ xb1, const float* __restrict__ xb2,
    const float* __restrict__ ub1, const float* __restrict__ ub2,
    const float* __restrict__ xb3, const float* __restrict__ ub3,
    const float* __restrict__ cb, float* __restrict__ wp) {
    int i = blockIdx.x * 256 + threadIdx.x;
    if (i >= L_TOT) return;
    float v = 0.0f;
    if (i < 1360) {
        int o = i / 68, c = i - o * 68;
        if (c == 0) v = xw1[o * 65];
        else if (c >= 4) v = xw1[o * 65 + c - 3];
    } else if (i < 2720) {
        int j = i - 1360; int o = j / 68, c = j - o * 68;
        if (c == 0) v = uw1[o * 65];
        else if (c >= 4) v = uw1[o * 65 + c - 3];
    } else if (i < 3120) v = xw2[i - 2720];
    else if (i < 3520) v = uw2[i - 3120];
    else if (i < 4800) v = xw3[i - 3520];
    else if (i < 6080) v = uw3[i - 4800];
    else if (i < 14272) {
        int j = i - 6080; int row = j >> 6, s = j & 63;
        v = cw[s * 128 + row];
    }
    else if (i < 14292) v = xb1[i - 14272];
    else if (i < 14312) v = xb2[i - 14292];
    else if (i < 14332) v = ub1[i - 14312];
    else if (i < 14352) v = ub2[i - 14332];
    else if (i < 14416) v = xb3[i - 14352];
    else if (i < 14480) v = ub3[i - 14416];
    else v = cb[i - 14480];
    wp[i] = v;
}

// ---- shared MLP helpers (read LDS weight block) ----
template <int OW1, int OB1, int OW2, int OB2>
__device__ __forceinline__ void mlp20(const float* __restrict__ sm,
                                      float tval, const float4* z, float* h2) {
    float h1[20];
#pragma unroll 4
    for (int o = 0; o < 20; ++o) {
        const int ro = OW1 + o * 68;
        float a = sm[OB1 + o] + tval * sm[ro];
        const float4* wr = reinterpret_cast<const float4*>(&sm[ro + 4]);
#pragma unroll
        for (int v = 0; v < 16; ++v) {
            float4 w4 = wr[v];
            a += z[v].x * w4.x + z[v].y * w4.y + z[v].z * w4.z + z[v].w * w4.w;
        }
        h1[o] = fast_sigmoid(a);
    }
#pragma unroll 4
    for (int o = 0; o < 20; ++o) {
        float a = sm[OB2 + o];
        const float4* wr = reinterpret_cast<const float4*>(&sm[OW2 + o * 20]);
#pragma unroll
        for (int v = 0; v < 5; ++v) {
            float4 w4 = wr[v];
            a += h1[4*v+0]*w4.x + h1[4*v+1]*w4.y + h1[4*v+2]*w4.z + h1[4*v+3]*w4.w;
        }
        h2[o] = fast_sigmoid(a);
    }
}

template <int OW3, int OB3, int OCWT>
__device__ __forceinline__ void final64(const float* __restrict__ sm,
                                        const float* h2, float* oacc) {
#pragma unroll 2
    for (int o = 0; o < 64; ++o) {
        float a = sm[OB3 + o];
        const float4* wr = reinterpret_cast<const float4*>(&sm[OW3 + o * 20]);
#pragma unroll
        for (int v = 0; v < 5; ++v) {
            float4 w4 = wr[v];
            a += h2[4*v+0]*w4.x + h2[4*v+1]*w4.y + h2[4*v+2]*w4.z + h2[4*v+3]*w4.w;
        }
        float s = fast_sigmoid(a);
        const float4* cr = reinterpret_cast<const float4*>(&sm[OCWT + o * 64]);
#pragma unroll
        for (int v = 0; v < 16; ++v) {
            float4 c4 = cr[v];
            oacc[4*v+0] += s * c4.x; oacc[4*v+1] += s * c4.y;
            oacc[4*v+2] += s * c4.z; oacc[4*v+3] += s * c4.w;
        }
    }
}

// ---- K_MAIN ----
// block 0 = RNN chain: 4 waves, 1 barrier/step.
//   Each wave q computes partial_q[i] = sum_{j in [16q,16q+16)} W[i][j] h[j]
//   (lane i = output i), writes part[pp][q][i], barrier, then EVERY lane of
//   EVERY wave reads the 4 partials for its own i and computes h_i = tanh(.)
//   redundantly. Wave q's lanes 16q..16q+15 then hold exactly the h-values
//   wave q needs next step -> 16-lane masked write to wave-PRIVATE hq[q][16]
//   + 4 uniform b128 reads, no second barrier (same-wave in-order LDS).
//   part[] ping-pongs on step parity (max barrier skew = 1 -> race-free).
//   Global traffic (pre prefetch, hseq flush) issues once per 64-step chunk.
// blocks 1..1024 = state branch (out = cb + state contribution).
#define SMEM_FLOATS 16960   // pre2 8192 + hs2 8192 + hq 64 + part 512

__global__ __launch_bounds__(256) void k_main(
    const float* __restrict__ t_in, const float* __restrict__ x_in,
    const float* __restrict__ i2h_w,
    const float* __restrict__ pre_i,
    const float* __restrict__ wp,
    float* __restrict__ hseq, float* __restrict__ out) {
    __shared__ float smem[SMEM_FLOATS];
    const int tid = threadIdx.x;
    const int bid = blockIdx.x;

    if (bid == 0) {
        float* pre2 = smem;            // [2][4096]
        float* hs2  = smem + 8192;     // [2][4096]
        float* hq   = smem + 16384;    // [4][16]
        float* part = smem + 16448;    // [2][4][64]
        const int lane = tid & 63;
        const int wv = tid >> 6;

        float wih[16];
#pragma unroll
        for (int j = 0; j < 16; ++j) wih[j] = i2h_w[lane * 72 + 8 + 16 * wv + j];

        // prologue: stage pre chunk 0
        {
            const float4* pg = reinterpret_cast<const float4*>(pre_i);
            float4* pd = reinterpret_cast<float4*>(pre2);
#pragma unroll
            for (int j = 0; j < 4; ++j) pd[tid * 4 + j] = pg[tid * 4 + j];
        }
        float h = 0.0f;
        __syncthreads();

        float4 pl0, pl1, pl2, pl3;
        for (int c = 0; c < NCHUNK; ++c) {
            const int cb = c & 1;
            const float* pre_c = pre2 + cb * 4096;
            float* hs_c = hs2 + cb * 4096;
            // issue next-chunk pre loads (in flight across this chunk)
            if (c + 1 < NCHUNK) {
                const float4* pg = reinterpret_cast<const float4*>(pre_i + (c + 1) * 4096);
                pl0 = pg[tid*4+0]; pl1 = pg[tid*4+1]; pl2 = pg[tid*4+2]; pl3 = pg[tid*4+3];
            }
            // flush previous chunk's h history to hseq (stores drain at next barrier, once)
            if (c >= 1) {
                const float4* hsrc = reinterpret_cast<const float4*>(hs2 + (cb ^ 1) * 4096);
                float4* hdst = reinterpret_cast<float4*>(hseq + (c - 1) * 4096);
                float4 s0 = hsrc[tid*4+0], s1 = hsrc[tid*4+1], s2 = hsrc[tid*4+2], s3 = hsrc[tid*4+3];
                hdst[tid*4+0] = s0; hdst[tid*4+1] = s1; hdst[tid*4+2] = s2; hdst[tid*4+3] = s3;
            }
#pragma unroll 2
            for (int s = 0; s < CHUNK; ++s) {
                const int pp = s & 1;
                if (wv == 0) hs_c[s * 64 + lane] = h;         // h BEFORE step
                if ((lane >> 4) == wv) hq[wv * 16 + (lane & 15)] = h;
                float a0 = (wv == 0) ? pre_c[s * 64 + lane] : 0.0f;
                const float4* hb = reinterpret_cast<const float4*>(hq + wv * 16);
                float4 b0 = hb[0], b1 = hb[1], b2 = hb[2], b3 = hb[3];
                float a1 = 0.0f, a2 = 0.0f, a3 = 0.0f;
                a0 += wih[ 0]*b0.x + wih[ 1]*b0.y + wih[ 2]*b0.z + wih[ 3]*b0.w;
                a1 += wih[ 4]*b1.x + wih[ 5]*b1.y + wih[ 6]*b1.z + wih[ 7]*b1.w;
                a2 += wih[ 8]*b2.x + wih[ 9]*b2.y + wih[10]*b2.z + wih[11]*b2.w;
                a3 += wih[12]*b3.x + wih[13]*b3.y + wih[14]*b3.z + wih[15]*b3.w;
                part[pp * 256 + wv * 64 + lane] = (a0 + a1) + (a2 + a3);
                __syncthreads();
                float p0 = part[pp * 256 +   0 + lane];
                float p1 = part[pp * 256 +  64 + lane];
                float p2 = part[pp * 256 + 128 + lane];
                float p3 = part[pp * 256 + 192 + lane];
                h = fast_tanh((p0 + p1) + (p2 + p3));
            }
            // stage pre chunk c+1 (loads already in registers)
            if (c + 1 < NCHUNK) {
                float4* pd = reinterpret_cast<float4*>(pre2 + ((c + 1) & 1) * 4096);
                pd[tid*4+0] = pl0; pd[tid*4+1] = pl1; pd[tid*4+2] = pl2; pd[tid*4+3] = pl3;
            }
            __syncthreads();
        }
        {   // epilogue: flush final chunk's history
            const float4* hsrc = reinterpret_cast<const float4*>(hs2 + ((NCHUNK - 1) & 1) * 4096);
            float4* hdst = reinterpret_cast<float4*>(hseq + (NCHUNK - 1) * 4096);
#pragma unroll
            for (int j = 0; j < 4; ++j) hdst[tid * 4 + j] = hsrc[tid * 4 + j];
        }
        return;
    }

    // ---- state-branch blocks ----
    {
        float4* s4 = reinterpret_cast<float4*>(smem);
        const float4* w4 = reinterpret_cast<const float4*>(wp);
        for (int idx = tid; idx < L_TOT / 4; idx += 256) s4[idx] = w4[idx];
    }
    __syncthreads();

    const int r = (bid - 1) * 256 + tid;
    float tval = t_in[r];
    float4 z[16];
    const float4* xp = reinterpret_cast<const float4*>(x_in + (size_t)r * 64);
#pragma unroll
    for (int v = 0; v < 16; ++v) z[v] = xp[v];

    float h2[20];
    mlp20<L_XW1, L_XB1, L_XW2, L_XB2>(smem, tval, z, h2);

    float oacc[64];
    {
        const float4* cbp = reinterpret_cast<const float4*>(&smem[L_CB]);
#pragma unroll
        for (int v = 0; v < 16; ++v) {
            float4 c4 = cbp[v];
            oacc[4*v+0] = c4.x; oacc[4*v+1] = c4.y;
            oacc[4*v+2] = c4.z; oacc[4*v+3] = c4.w;
        }
    }
    final64<L_XW3, L_XB3, L_CWT>(smem, h2, oacc);

    float4* op = reinterpret_cast<float4*>(out + (size_t)r * 64);
#pragma unroll
    for (int v = 0; v < 16; ++v) {
        float4 f;
        f.x = oacc[4*v+0]; f.y = oacc[4*v+1];
        f.z = oacc[4*v+2]; f.w = oacc[4*v+3];
        op[v] = f;
    }
}

// ---- K_CTRL: control branch, accumulates into out ----
__global__ __launch_bounds__(256) void k_ctrl(
    const float* __restrict__ t_in, const float* __restrict__ uo,
    const float* __restrict__ wp, float* __restrict__ out) {
    __shared__ float sm[L_TOT];
    const int tid = threadIdx.x;
    {
        float4* s4 = reinterpret_cast<float4*>(sm);
        const float4* w4 = reinterpret_cast<const float4*>(wp);
        for (int idx = tid; idx < L_TOT / 4; idx += 256) s4[idx] = w4[idx];
    }
    __syncthreads();

    const int r = blockIdx.x * 256 + tid;
    float tval = t_in[r];
    int ti = min((int)(tval * 1024.0f), 1023);
    float4 z[16];
    const float4* ep = reinterpret_cast<const float4*>(uo + ti * 64);
#pragma unroll
    for (int v = 0; v < 16; ++v) z[v] = ep[v];

    float h2[20];
    mlp20<L_UW1, L_UB1, L_UW2, L_UB2>(sm, tval, z, h2);

    float oacc[64];
    float4* op = reinterpret_cast<float4*>(out + (size_t)r * 64);
#pragma unroll
    for (int v = 0; v < 16; ++v) {
        float4 f = op[v];
        oacc[4*v+0] = f.x; oacc[4*v+1] = f.y;
        oacc[4*v+2] = f.z; oacc[4*v+3] = f.w;
    }
    final64<L_UW3, L_UB3, L_CWT + 64 * 64>(sm, h2, oacc);
#pragma unroll
    for (int v = 0; v < 16; ++v) {
        float4 f;
        f.x = oacc[4*v+0]; f.y = oacc[4*v+1];
        f.z = oacc[4*v+2]; f.w = oacc[4*v+3];
        op[v] = f;
    }
}

extern "C" void kernel_launch(void* const* d_in, const int* in_sizes, int n_in,
                              void* d_out, int out_size, void* d_ws, size_t ws_size,
                              hipStream_t stream) {
    const float* t     = (const float*)d_in[0];
    const float* x     = (const float*)d_in[1];
    const float* u     = (const float*)d_in[2];
    const float* i2h_w = (const float*)d_in[3];
    const float* i2h_b = (const float*)d_in[4];
    const float* h2o_w = (const float*)d_in[5];
    const float* h2o_b = (const float*)d_in[6];
    const float* xw1 = (const float*)d_in[7];  const float* xb1 = (const float*)d_in[8];
    const float* xw2 = (const float*)d_in[9];  const float* xb2 = (const float*)d_in[10];
    const float* xw3 = (const float*)d_in[11]; const float* xb3 = (const float*)d_in[12];
    const float* uw1 = (const float*)d_in[13]; const float* ub1 = (const float*)d_in[14];
    const float* uw2 = (const float*)d_in[15]; const float* ub2 = (const float*)d_in[16];
    const float* uw3 = (const float*)d_in[17]; const float* ub3 = (const float*)d_in[18];
    const float* cw  = (const float*)d_in[19]; const float* cb  = (const float*)d_in[20];
    float* out = (float*)d_out;

    float* ws = (float*)d_ws;
    // uo aliases pre_i (pre_i dead after k_main; uo written by k_rnn_out after)
    float* pre_i = ws;                 // [0,      65536)
    float* uo    = ws;                 //   alias, used post-k_main
    float* pre_o = ws + 65536;         // [65536, 131072)
    float* hseq  = ws + 131072;        // [131072,196608)
    float* wp    = ws + 196608;        // [196608,211152)

    int Bv = in_sizes[0];              // 262144

    hipLaunchKernelGGL(k_repack, dim3((L_TOT + 255) / 256), dim3(256), 0, stream,
                       xw1, uw1, xw2, uw2, xw3, uw3, cw,
                       xb1, xb2, ub1, ub2, xb3, ub3, cb, wp);
    hipLaunchKernelGGL(k_rnn_pre, dim3(256), dim3(256), 0, stream,
                       u, i2h_w, i2h_b, h2o_w, h2o_b, pre_i, pre_o);
    hipLaunchKernelGGL(k_main, dim3(1 + Bv / 256), dim3(256), 0, stream,
                       t, x, i2h_w, pre_i, wp, hseq, out);
    hipLaunchKernelGGL(k_rnn_out, dim3(T_SEQ), dim3(64), 0, stream,
                       h2o_w, pre_o, hseq, uo);
    hipLaunchKernelGGL(k_ctrl, dim3(Bv / 256), dim3(256), 0, stream,
                       t, uo, wp, out);
}